// Round 5
// baseline (524.600 us; speedup 1.0000x reference)
//
#include <hip/hip_runtime.h>

// out[b] = 0.75 * sum_i x[b,i] * s[i],  s[i] = sum_h W[h,i]
// x: [2048, 8192] f32 ; W: [8192, 8192] f32 ; out: [2048] f32
//
// 2 dispatches: memset(s+counter) ; ONE fused kernel (colsum -> grid
// spin-barrier -> rowdot). Deadlock-free by construction:
// __launch_bounds__(256,4) guarantees >=4 blocks/CU, grid = 256 CU * 4.

#define I_SIZE 8192
#define H_SIZE 8192
#define BATCH  2048
#define NB     1024   // = 256 CUs * 4 blocks/CU, all resident simultaneously

__global__ __launch_bounds__(256, 4) void fused_kernel(
    const float* __restrict__ x, const float* __restrict__ W,
    float* __restrict__ s, unsigned* __restrict__ counter,
    float* __restrict__ out) {
  const int t = threadIdx.x;
  const int bid = blockIdx.x;

  // ---- Phase A: panel colsum (R1-proven pattern) ---------------------------
  // 8 column panels x 128 row chunks. Block reads 4KB/row, 64 rows.
  {
    const int px = bid & 7;          // column panel
    const int py = bid >> 3;         // row chunk
    const int col = px * 1024 + t * 4;
    const float* base = W + (size_t)py * 64 * I_SIZE + col;

    float4 acc = make_float4(0.f, 0.f, 0.f, 0.f);
#pragma unroll 8
    for (int r = 0; r < 64; ++r) {
      float4 v = *reinterpret_cast<const float4*>(base + (size_t)r * I_SIZE);
      acc.x += v.x; acc.y += v.y; acc.z += v.z; acc.w += v.w;
    }
    atomicAdd(&s[col + 0], acc.x);   // device-scope: executes at coherent point
    atomicAdd(&s[col + 1], acc.y);
    atomicAdd(&s[col + 2], acc.z);
    atomicAdd(&s[col + 3], acc.w);
  }

  // ---- Grid barrier (hand-rolled; all NB blocks are resident) --------------
  __threadfence();                   // release: drain s-atomics (vmcnt)
  __syncthreads();
  if (t == 0) {
    __hip_atomic_fetch_add(counter, 1u, __ATOMIC_ACQ_REL, __HIP_MEMORY_SCOPE_AGENT);
    unsigned v;
    do {
      __builtin_amdgcn_s_sleep(2);
      v = __hip_atomic_load(counter, __ATOMIC_ACQUIRE, __HIP_MEMORY_SCOPE_AGENT);
    } while (v < NB);
  }
  __syncthreads();
  __threadfence();                   // acquire: invalidate L1 before reading s

  // ---- Phase B: rowdot, rows 2*bid and 2*bid+1 (R1-proven shape) -----------
  {
    const float* x0 = x + (size_t)(2 * bid) * I_SIZE;
    const float* x1 = x0 + I_SIZE;
    float a0 = 0.f, a1 = 0.f;
#pragma unroll
    for (int j = 0; j < 8; ++j) {
      const int i = t * 4 + j * 1024;
      const float4 sv = *reinterpret_cast<const float4*>(s + i);
      const float4 v0 = *reinterpret_cast<const float4*>(x0 + i);
      const float4 v1 = *reinterpret_cast<const float4*>(x1 + i);
      a0 += v0.x * sv.x + v0.y * sv.y + v0.z * sv.z + v0.w * sv.w;
      a1 += v1.x * sv.x + v1.y * sv.y + v1.z * sv.z + v1.w * sv.w;
    }
#pragma unroll
    for (int off = 32; off; off >>= 1) {
      a0 += __shfl_down(a0, off, 64);
      a1 += __shfl_down(a1, off, 64);
    }
    __shared__ float p0[4], p1[4];
    const int lane = t & 63, wid = t >> 6;
    if (lane == 0) { p0[wid] = a0; p1[wid] = a1; }
    __syncthreads();
    if (t == 0) out[2 * bid]     = 0.75f * (p0[0] + p0[1] + p0[2] + p0[3]);
    if (t == 1) out[2 * bid + 1] = 0.75f * (p1[0] + p1[1] + p1[2] + p1[3]);
  }
}

extern "C" void kernel_launch(void* const* d_in, const int* in_sizes, int n_in,
                              void* d_out, int out_size, void* d_ws, size_t ws_size,
                              hipStream_t stream) {
  const float* x = (const float*)d_in[0];   // [BATCH, I_SIZE]
  const float* W = (const float*)d_in[1];   // [H_SIZE, I_SIZE]
  float* out = (float*)d_out;               // [BATCH]

  float*    s       = (float*)d_ws;                         // 32 KiB
  unsigned* counter = (unsigned*)((char*)d_ws + 32768);     // 4 B

  // zero s + counter in one async memset (graph-capture-safe)
  hipMemsetAsync(d_ws, 0, 32768 + sizeof(unsigned), stream);

  fused_kernel<<<NB, 256, 0, stream>>>(x, W, s, counter, out);
}

// Round 6
// 80.576 us; speedup vs baseline: 6.5106x; 6.5106x over previous
//
#include <hip/hip_runtime.h>

// out[b] = 0.75 * sum_i x[b,i] * s[i],  s[i] = sum_h W[h,i]
// x: [2048, 8192] f32 ; W: [8192, 8192] f32 ; out: [2048] f32
//
// R1-proven 3-dispatch structure; colsum reworked for latency hiding:
//   memset(s) ; colsum (2048 blocks, 2 independent row-streams/thread,
//   atomicAdd into s) ; rowdot (2048 blocks, 1 row each — R1 exact).

#define I_SIZE 8192
#define H_SIZE 8192
#define BATCH  2048

// ---- Kernel 1: panel colsum, 2048 blocks x 32 rows ------------------------
// bid&7 = column panel (1024 floats), bid>>3 = row chunk (32 rows).
// Each thread owns 4 consecutive columns; two independent 16-row streams
// keep ~16 float4 loads in flight.
__global__ __launch_bounds__(256) void colsum_kernel(const float* __restrict__ W,
                                                     float* __restrict__ s) {
    const int t   = threadIdx.x;
    const int px  = blockIdx.x & 7;
    const int py  = blockIdx.x >> 3;          // 0..255
    const int col = px * 1024 + t * 4;
    const float* base = W + (size_t)py * 32 * I_SIZE + col;

    float4 a0 = make_float4(0.f, 0.f, 0.f, 0.f);
    float4 a1 = make_float4(0.f, 0.f, 0.f, 0.f);
    const float* b0 = base;
    const float* b1 = base + (size_t)16 * I_SIZE;
#pragma unroll 8
    for (int r = 0; r < 16; ++r) {
        float4 v0 = *reinterpret_cast<const float4*>(b0 + (size_t)r * I_SIZE);
        float4 v1 = *reinterpret_cast<const float4*>(b1 + (size_t)r * I_SIZE);
        a0.x += v0.x; a0.y += v0.y; a0.z += v0.z; a0.w += v0.w;
        a1.x += v1.x; a1.y += v1.y; a1.z += v1.z; a1.w += v1.w;
    }
    atomicAdd(&s[col + 0], a0.x + a1.x);
    atomicAdd(&s[col + 1], a0.y + a1.y);
    atomicAdd(&s[col + 2], a0.z + a1.z);
    atomicAdd(&s[col + 3], a0.w + a1.w);
}

// ---- Kernel 2: out[b] = 0.75 * dot(x[b], s) — R1 exact --------------------
__global__ __launch_bounds__(256) void rowdot_kernel(const float* __restrict__ x,
                                                     const float* __restrict__ s,
                                                     float* __restrict__ out) {
    const int b = blockIdx.x;
    const float* xr = x + (size_t)b * I_SIZE;

    float acc = 0.f;
#pragma unroll
    for (int i = threadIdx.x * 4; i < I_SIZE; i += 256 * 4) {
        float4 xv = *reinterpret_cast<const float4*>(xr + i);
        float4 sv = *reinterpret_cast<const float4*>(s + i);
        acc += xv.x * sv.x + xv.y * sv.y + xv.z * sv.z + xv.w * sv.w;
    }

#pragma unroll
    for (int off = 32; off; off >>= 1)
        acc += __shfl_down(acc, off, 64);

    __shared__ float partial[4];
    const int lane = threadIdx.x & 63;
    const int wid  = threadIdx.x >> 6;
    if (lane == 0) partial[wid] = acc;
    __syncthreads();
    if (threadIdx.x == 0)
        out[b] = 0.75f * (partial[0] + partial[1] + partial[2] + partial[3]);
}

extern "C" void kernel_launch(void* const* d_in, const int* in_sizes, int n_in,
                              void* d_out, int out_size, void* d_ws, size_t ws_size,
                              hipStream_t stream) {
    const float* x = (const float*)d_in[0];   // [BATCH, I_SIZE]
    const float* W = (const float*)d_in[1];   // [H_SIZE, I_SIZE]
    float* out = (float*)d_out;               // [BATCH]
    float* s   = (float*)d_ws;                // [I_SIZE] column sums

    hipMemsetAsync(s, 0, I_SIZE * sizeof(float), stream);
    colsum_kernel<<<2048, 256, 0, stream>>>(W, s);
    rowdot_kernel<<<BATCH, 256, 0, stream>>>(x, s, out);
}